// Round 10
// baseline (494.730 us; speedup 1.0000x reference)
//
#include <hip/hip_runtime.h>
#include <math.h>

// Problem constants
#define DM    512
#define DI    1024
#define DSN   16
#define DTR   32
#define DFFN  2048
#define BB    8
#define SS    512
#define TTM   1024
#define LCAT  1536
#define CONV_R 8      // rows per conv thread (weight-load amortization)

#define ACT_NONE     0
#define ACT_RELU     1
#define ACT_DELTA    3   // softplus+bias -> Cb(delta bf16, stride 1024)
#define ACT_XDBL     4   // fp32 partials (n<64) -> C2[(z*M+m)*64+n]; combined later

typedef __attribute__((ext_vector_type(8))) short short8;
typedef __attribute__((ext_vector_type(8))) unsigned short ushort8;
typedef __attribute__((ext_vector_type(4))) float f32x4;

#define L2E 1.4426950408889634f

__device__ __forceinline__ unsigned short f2b(float f) {
    unsigned int u = __float_as_uint(f);
    return (unsigned short)((u + 0x7FFFu + ((u >> 16) & 1u)) >> 16);
}
__device__ __forceinline__ float b2f(unsigned short h) {
    return __uint_as_float(((unsigned int)h) << 16);
}
__device__ __forceinline__ float fast_softplus(float v) {
    return (v > 20.f) ? v : __logf(1.f + __expf(v));
}
__device__ __forceinline__ float fexp2(float x) {
#if __has_builtin(__builtin_amdgcn_exp2f)
    return __builtin_amdgcn_exp2f(x);
#else
    float r; asm("v_exp_f32 %0, %1" : "=v"(r) : "v"(x)); return r;
#endif
}
__device__ __forceinline__ float frcp(float x) {
    return __builtin_amdgcn_rcpf(x);
}
__device__ __forceinline__ void gld16(const void* g, void* l) {
    __builtin_amdgcn_global_load_lds(
        (const __attribute__((address_space(1))) void*)g,
        (__attribute__((address_space(3))) void*)l, 16, 0, 0);
}

__device__ __forceinline__ int map_row(int m, int mb, int bs, int ro) {
    int q = m / mb;
    return q * bs + ro + (m - q * mb);
}

// ================= bf16 MFMA GEMM: C[row(m),n] = act(A[row(m),k] * W[n,k] + bias[n])
// Tile 128x128, BK=64. Full 3-bit XOR LDS swizzle (bank-conflict-free b128 reads).
// Scalar three-branch epilogue. ysplit merges two sub-problems in one grid.
// Split-K via gridDim.z: z>0 writes fp32 partials to Cf2 + (z-1)*pstr
// (ACT_NONE) or C2[(z*M+m)*64+n] (ACT_XDBL).
__global__ __launch_bounds__(256) void mgemm_kernel(
    const unsigned short* __restrict__ A, int mb, int bs, int ro,
    const unsigned short* __restrict__ W, const float* __restrict__ bias,
    float* __restrict__ Cf, unsigned short* __restrict__ Cb,
    float* __restrict__ C2, float* __restrict__ Cf2,
    int N, int K, int act,
    int omb, int obs, int oro, int ldc, int nofs, int pstr,
    int ysplit, int amb2, int abs2, int aro2, int wofs2,
    int omb2, int obs2, int oro2, int nofs2)
{
    __shared__ __align__(16) unsigned short As[128 * 64];
    __shared__ __align__(16) unsigned short Bs[128 * 64];
    int tid = threadIdx.x;
    int lane = tid & 63, wave = tid >> 6;
    int wy = wave >> 1, wx = wave & 1;
    int bx = blockIdx.x, by = blockIdx.y;
    int nx = gridDim.x, ny = gridDim.y;
    const unsigned short* Wp = W;
    if (ysplit) {
        if (by >= ysplit) {
            by -= ysplit; ny = gridDim.y - ysplit;
            mb = amb2; bs = abs2; ro = aro2; Wp += wofs2;
            omb = omb2; obs = obs2; oro = oro2; nofs = nofs2;
        } else ny = ysplit;
    }
    // XCD-band swizzle over (bx,by) within the (sub-)grid; z reuses mapping
    int f = by * nx + bx;
    int xcd = f & 7, j2 = f >> 3;
    int bandh = ny >> 3;
    int m0 = (xcd * bandh + j2 / nx) * 128;
    int n0 = (j2 % nx) * 128;
    // split-K
    int Kh = K / gridDim.z;
    int kbeg = blockIdx.z * Kh, kend = kbeg + Kh;
    float* Cfo = Cf;
    const float* biaso = bias;
    if (blockIdx.z) { Cfo = Cf2 + (size_t)(blockIdx.z - 1) * pstr; biaso = nullptr; }

    // staging: wave stages chunk positions c = wave*256 + j*64 + lane (j=0..3)
    unsigned aoff[4], boff[4];
    unsigned short* la[4];
    unsigned short* lb[4];
    #pragma unroll
    for (int j = 0; j < 4; j++) {
        int c  = wave * 256 + j * 64 + lane;
        int r  = c >> 3;                    // tile row 0..127
        int q  = c & 7;
        int g  = q ^ (r & 7);               // un-swizzled k-chunk 0..7 (3-bit XOR)
        int arow = map_row(m0 + r, mb, bs, ro);
        aoff[j] = (unsigned)(arow * K + g * 8);
        boff[j] = (unsigned)((n0 + r) * K + g * 8);
        la[j] = As + (size_t)(wave * 256 + j * 64) * 8;   // chunk pos * 8 shorts
        lb[j] = Bs + (size_t)(wave * 256 + j * 64) * 8;
    }
    // fragment read bases; R&7 == fm&7 (wy*64, t*16 are multiples of 8/16)
    int fm = lane & 15, fg = lane >> 4;
    int sw = fg ^ (fm & 3);
    int b2 = (fm >> 2) & 1;
    const unsigned short* arp = As + ((size_t)(wy * 64 + fm) * 8 + sw) * 8;
    const unsigned short* brp = Bs + ((size_t)(wx * 64 + fm) * 8 + sw) * 8;

    f32x4 acc[4][4];
    #pragma unroll
    for (int i = 0; i < 4; i++)
        #pragma unroll
        for (int j = 0; j < 4; j++) acc[i][j] = 0.f;

    for (int k0 = kbeg; k0 < kend; k0 += 64) {
        #pragma unroll
        for (int j = 0; j < 4; j++) {
            gld16(A  + aoff[j] + k0, la[j]);
            gld16(Wp + boff[j] + k0, lb[j]);
        }
        __syncthreads();
        #pragma unroll
        for (int h = 0; h < 2; h++) {
            int ho = ((h ^ b2) * 32);
            short8 af[4], bfr[4];
            #pragma unroll
            for (int t = 0; t < 4; t++) af[t]  = *(const short8*)(arp + ho + t * 1024);
            #pragma unroll
            for (int t = 0; t < 4; t++) bfr[t] = *(const short8*)(brp + ho + t * 1024);
            #pragma unroll
            for (int i = 0; i < 4; i++)
                #pragma unroll
                for (int j = 0; j < 4; j++)
                    acc[i][j] = __builtin_amdgcn_mfma_f32_16x16x32_bf16(af[i], bfr[j], acc[i][j], 0, 0, 0);
        }
        __syncthreads();
    }

    // epilogue: C/D layout col=lane&15 (n), row=(lane>>4)*4+reg (m)
    int en = lane & 15, em = (lane >> 4) * 4;
    if (act == ACT_XDBL) {
        size_t zb = (size_t)blockIdx.z * omb;
        #pragma unroll
        for (int j = 0; j < 4; j++) {
            int n = n0 + wx * 64 + j * 16 + en;
            if (n >= 64) continue;
            #pragma unroll
            for (int i = 0; i < 4; i++) {
                int mbase = m0 + wy * 64 + i * 16 + em;
                #pragma unroll
                for (int r = 0; r < 4; r++)
                    C2[(zb + mbase + r) * 64 + n] = acc[i][j][r];
            }
        }
        return;
    }
    if (act == ACT_DELTA) {
        #pragma unroll
        for (int j = 0; j < 4; j++) {
            int n = n0 + wx * 64 + j * 16 + en;
            float bv = bias[n];
            #pragma unroll
            for (int i = 0; i < 4; i++) {
                int mbase = m0 + wy * 64 + i * 16 + em;
                #pragma unroll
                for (int r = 0; r < 4; r++) {
                    float v = acc[i][j][r] + bv;
                    Cb[(size_t)(mbase + r) * 1024 + n] = f2b(fast_softplus(v));
                }
            }
        }
        return;
    }
    #pragma unroll
    for (int j = 0; j < 4; j++) {
        int n = n0 + wx * 64 + j * 16 + en;
        float bv = biaso ? biaso[n] : 0.f;
        #pragma unroll
        for (int i = 0; i < 4; i++) {
            int mbase = m0 + wy * 64 + i * 16 + em;
            #pragma unroll
            for (int r = 0; r < 4; r++) {
                float v = acc[i][j][r] + bv;
                if (act == ACT_RELU) v = v > 0.f ? v : 0.f;
                int orow = map_row(mbase + r, omb, obs, oro);
                size_t off = (size_t)orow * ldc + nofs + n;
                if (Cb) Cb[off] = f2b(v);
                else    Cfo[off] = v;
            }
        }
    }
}

// ================= R20: counted-vmcnt 2-deep pipelined GEMM (T3/T4 minimum)
// 128x128 tile, 512 threads (8 waves, 2Mx4N grid, acc[4][2]), double-buffered
// 64KB LDS. Raw s_barrier + inline-asm vmcnt(4) (NEVER 0 in steady state):
// stage t+1's 4 loads stay in flight across the barrier; stage t+2 is issued
// BEFORE the MFMA cluster so HBM latency hides under compute. sched_barrier(0)
// after every wait/barrier (rule #18: hipcc hoists reg-only MFMA past asm
// waits). Same 3-bit-XOR swizzle + fragment math as mgemm_kernel. bf16 out
// only (NONE/RELU + bias); full-K (no split-K); ysplit as in mgemm_kernel.
__global__ __launch_bounds__(512, 4) void mgemm_pipe(
    const unsigned short* __restrict__ A, int mb, int bs, int ro,
    const unsigned short* __restrict__ W, const float* __restrict__ bias,
    unsigned short* __restrict__ Cb, int K, int act,
    int omb, int obs, int oro, int ldc, int nofs,
    int ysplit, int amb2, int abs2, int aro2, int wofs2,
    int omb2, int obs2, int oro2, int nofs2)
{
    __shared__ __align__(16) unsigned short smem[32768];   // 2 x (A 16KB | B 16KB)
    int tid = threadIdx.x;
    int lane = tid & 63, wave = tid >> 6;
    int wy = wave >> 2, wx = wave & 3;       // 2x4 wave grid: 64x32 out per wave
    int bx = blockIdx.x, by = blockIdx.y;
    int nx = gridDim.x, ny = gridDim.y;
    const unsigned short* Wp = W;
    if (ysplit) {
        if (by >= ysplit) {
            by -= ysplit; ny = gridDim.y - ysplit;
            mb = amb2; bs = abs2; ro = aro2; Wp += wofs2;
            omb = omb2; obs = obs2; oro = oro2; nofs = nofs2;
        } else ny = ysplit;
    }
    int f = by * nx + bx;
    int xcd = f & 7, j2 = f >> 3;
    int bandh = ny >> 3;
    int m0 = (xcd * bandh + j2 / nx) * 128;
    int n0 = (j2 % nx) * 128;

    // staging: 2 chunk-positions per thread per operand (1024 positions total)
    int c0 = tid, c1 = tid + 512;
    int r0 = c0 >> 3, g0 = (c0 & 7) ^ (r0 & 7);
    int r1 = c1 >> 3, g1 = (c1 & 7) ^ (r1 & 7);
    unsigned ga0 = (unsigned)(map_row(m0 + r0, mb, bs, ro) * K + g0 * 8);
    unsigned ga1 = (unsigned)(map_row(m0 + r1, mb, bs, ro) * K + g1 * 8);
    unsigned gb0 = (unsigned)((n0 + r0) * K + g0 * 8);
    unsigned gb1 = (unsigned)((n0 + r1) * K + g1 * 8);
    // wave-uniform LDS bases (shorts); HW adds lane*16B
    int uA0 = wave * 512, uA1 = wave * 512 + 4096;
    int uB0 = 8192 + wave * 512, uB1 = 8192 + 4096 + wave * 512;

#define PSTAGE(kk, bofs) do { \
    gld16(A  + ga0 + (kk), smem + (bofs) + uA0); \
    gld16(Wp + gb0 + (kk), smem + (bofs) + uB0); \
    gld16(A  + ga1 + (kk), smem + (bofs) + uA1); \
    gld16(Wp + gb1 + (kk), smem + (bofs) + uB1); \
} while (0)

    int fm = lane & 15, fg = lane >> 4;
    int sw = fg ^ (fm & 3);
    int b2 = (fm >> 2) & 1;
    int arpO = (wy * 64 + fm) * 64 + sw * 8;          // shorts, A region
    int brpO = 8192 + (wx * 32 + fm) * 64 + sw * 8;   // shorts, B region

    f32x4 acc[4][2];
    #pragma unroll
    for (int i = 0; i < 4; i++)
        #pragma unroll
        for (int j = 0; j < 2; j++) acc[i][j] = 0.f;

    int nk = K >> 6;
    PSTAGE(0, 0);          // stage 0 -> buf0
    PSTAGE(64, 16384);     // stage 1 -> buf1  (8 loads outstanding)

    for (int t = 0; t < nk; ++t) {
        if (t + 1 < nk) { asm volatile("s_waitcnt vmcnt(4)" ::: "memory"); }
        else            { asm volatile("s_waitcnt vmcnt(0)" ::: "memory"); }
        __builtin_amdgcn_s_barrier();            // stage t visible block-wide
        __builtin_amdgcn_sched_barrier(0);
        int bo = (t & 1) << 14;                  // buffer offset in shorts
        short8 af[2][4], bfr[2][2];
        #pragma unroll
        for (int h = 0; h < 2; h++) {
            int ho = ((h ^ b2) << 5);
            #pragma unroll
            for (int i = 0; i < 4; i++)
                af[h][i] = *(const short8*)(smem + bo + arpO + ho + i * 1024);
            #pragma unroll
            for (int j = 0; j < 2; j++)
                bfr[h][j] = *(const short8*)(smem + bo + brpO + ho + j * 1024);
        }
        asm volatile("s_waitcnt lgkmcnt(0)" ::: "memory");
        __builtin_amdgcn_sched_barrier(0);
        __builtin_amdgcn_s_barrier();            // all waves done reading buf
        __builtin_amdgcn_sched_barrier(0);
        if (t + 2 < nk) PSTAGE((t + 2) * 64, bo);   // overwrite read-done buf
        #pragma unroll
        for (int h = 0; h < 2; h++)
            #pragma unroll
            for (int i = 0; i < 4; i++)
                #pragma unroll
                for (int j = 0; j < 2; j++)
                    acc[i][j] = __builtin_amdgcn_mfma_f32_16x16x32_bf16(
                        af[h][i], bfr[h][j], acc[i][j], 0, 0, 0);
    }
#undef PSTAGE

    // epilogue: col = n0 + wx*32 + j*16 + (lane&15); row = m0 + wy*64 + i*16 + (lane>>4)*4 + r
    int en = lane & 15, em = (lane >> 4) * 4;
    #pragma unroll
    for (int j = 0; j < 2; j++) {
        int n = n0 + wx * 32 + j * 16 + en;
        float bv = bias ? bias[n] : 0.f;
        #pragma unroll
        for (int i = 0; i < 4; i++) {
            int mbase = m0 + wy * 64 + i * 16 + em;
            #pragma unroll
            for (int r = 0; r < 4; r++) {
                float v = acc[i][j][r] + bv;
                if (act == ACT_RELU) v = v > 0.f ? v : 0.f;
                int orow = map_row(mbase + r, omb, obs, oro);
                Cb[(size_t)orow * ldc + nofs + n] = f2b(v);
            }
        }
    }
}

// ================= XDBL split-K combine: sum Z partials -> dt bf16 + bc fp32
__global__ __launch_bounds__(256) void xdbl_combine(
    const float* __restrict__ pxd, unsigned short* __restrict__ dtb,
    float* __restrict__ bcout, int M, int Z)
{
    int idx = blockIdx.x * 256 + threadIdx.x;     // m*16 + n4
    int m = idx >> 4, n4 = idx & 15;
    int n = n4 * 4;
    float4 s = make_float4(0.f, 0.f, 0.f, 0.f);
    for (int z = 0; z < Z; z++) {
        float4 p = *(const float4*)(pxd + ((size_t)z * M + m) * 64 + n);
        s.x += p.x; s.y += p.y; s.z += p.z; s.w += p.w;
    }
    if (n < 32) {
        ((ushort4*)(dtb + (size_t)m * 64))[n4] =
            make_ushort4(f2b(s.x), f2b(s.y), f2b(s.z), f2b(s.w));
    } else {
        *(float4*)(bcout + (size_t)m * 32 + (n - 32)) = s;
        ((ushort4*)(dtb + (size_t)m * 64))[n4] = make_ushort4(0, 0, 0, 0);  // zero dt pad
    }
}

// ================= fused prologue: all fp32->bf16 converts + padded weight fills
struct PrepPtrs {
    const float* tgt; const float* mem;
    const float* w[6];
    const float* xpj_s; const float* xpj_c;
    const float* dtw_s; const float* dtw_c;
    unsigned short* tgtb; unsigned short* catb; unsigned short* wb;
    unsigned short* xprojb_s; unsigned short* xprojb_c;
    unsigned short* dtwb_s; unsigned short* dtwb_c;
};
__global__ __launch_bounds__(256) void prep_kernel(PrepPtrs p)
{
    int u = blockIdx.x * 256 + threadIdx.x;
    if (u < 524288) {
        float4 v = ((const float4*)p.tgt)[u];
        ((ushort4*)p.tgtb)[u] = make_ushort4(f2b(v.x), f2b(v.y), f2b(v.z), f2b(v.w));
        return;
    }
    if (u < 1572864) {
        int f = u - 524288;
        int b = f >> 17, rem = f & 131071;          // per_b = 131072
        float4 v = ((const float4*)p.mem)[f];
        ((ushort4*)p.catb)[(size_t)b * 196608 + rem] =
            make_ushort4(f2b(v.x), f2b(v.y), f2b(v.z), f2b(v.w));
        return;
    }
    if (u < 2883584) {
        const int cum[7] = {0, 262144, 524288, 655360, 786432, 1048576, 1310720};
        int i = u - 1572864;
        int seg = 0;
        #pragma unroll
        for (int s = 1; s < 6; s++) seg += (i >= cum[s]);
        float4 v = ((const float4*)p.w[seg])[i - cum[seg]];
        ((ushort4*)p.wb)[i] = make_ushort4(f2b(v.x), f2b(v.y), f2b(v.z), f2b(v.w));
        return;
    }
    if (u < 2949120) {
        int i = u - 2883584;
        const float* src = p.xpj_s;
        unsigned short* dst = p.xprojb_s;
        if (i >= 32768) { i -= 32768; src = p.xpj_c; dst = p.xprojb_c; }
        int n = i >> 8;                             // out row (of 128)
        ushort4 o = make_ushort4(0, 0, 0, 0);
        if (n < 64) {
            float4 v = ((const float4*)src)[i];
            o = make_ushort4(f2b(v.x), f2b(v.y), f2b(v.z), f2b(v.w));
        }
        ((ushort4*)dst)[i] = o;
        return;
    }
    {
        int i = u - 2949120;
        const float* src = p.dtw_s;
        unsigned short* dst = p.dtwb_s;
        if (i >= 16384) { i -= 16384; src = p.dtw_c; dst = p.dtwb_c; }
        int n = i >> 4, c = (i & 15) * 4;
        ushort4 o = make_ushort4(0, 0, 0, 0);
        if (c < 32) {
            float4 v = *(const float4*)(src + n * 32 + c);
            o = make_ushort4(f2b(v.x), f2b(v.y), f2b(v.z), f2b(v.w));
        }
        ((ushort4*)dst)[i] = o;
    }
}

// ================= Depthwise causal conv (width 4) + bias + SiLU
__global__ __launch_bounds__(256) void conv_silu_kernel(
    const unsigned short* __restrict__ xz,
    const float* __restrict__ cw,
    const float* __restrict__ cb,
    unsigned short* __restrict__ xc, int L, int total)
{
    int idx = blockIdx.x * blockDim.x + threadIdx.x;
    if (idx >= total) return;
    int d8 = idx & 127;
    int d0 = d8 * 8;
    int t  = idx >> 7;                 // b*(L/CONV_R) + lq
    int nq = L / CONV_R;
    int b  = t / nq;
    int l0 = (t - b * nq) * CONV_R;
    size_t rbase = (size_t)b * L + l0;

    float4 wv[8];
    #pragma unroll
    for (int j = 0; j < 8; j++) wv[j] = *(const float4*)(cw + (d0 + j) * 4);
    float bias[8];
    {
        float4 c0 = ((const float4*)(cb + d0))[0];
        float4 c1 = ((const float4*)(cb + d0))[1];
        bias[0]=c0.x; bias[1]=c0.y; bias[2]=c0.z; bias[3]=c0.w;
        bias[4]=c1.x; bias[5]=c1.y; bias[6]=c1.z; bias[7]=c1.w;
    }
    ushort8 win[CONV_R + 3];
    #pragma unroll
    for (int k = 0; k < 3; k++) {
        ushort8 z;
        #pragma unroll
        for (int j = 0; j < 8; j++) z[j] = 0;
        win[k] = (l0 - 3 + k >= 0)
            ? *(const ushort8*)(xz + (rbase - 3 + k) * 2048 + d0) : z;
    }
    #pragma unroll
    for (int i = 0; i < CONV_R; i++)
        win[3 + i] = *(const ushort8*)(xz + (rbase + i) * 2048 + d0);

    const float* w = (const float*)&wv[0];
    #pragma unroll
    for (int i = 0; i < CONV_R; i++) {
        float acc[8];
        #pragma unroll
        for (int j = 0; j < 8; j++) acc[j] = bias[j];
        #pragma unroll
        for (int k = 0; k < 4; k++) {
            ushort8 v = win[i + k];
            #pragma unroll
            for (int j = 0; j < 8; j++)
                acc[j] = fmaf(b2f(v[j]), w[j * 4 + k], acc[j]);
        }
        ushort8 o;
        #pragma unroll
        for (int j = 0; j < 8; j++)
            o[j] = f2b(acc[j] * frcp(1.f + __expf(-acc[j])));
        *(ushort8*)(xc + (rbase + i) * 1024 + d0) = o;
    }
}

// ================= Chunked selective scan (delta bf16), CH = compile-time rows
// part_h layout [b][c][s][d] (R19 transpose: coalesced 4B lane-consecutive
// access). Full-chunk register preload in two halves; bc rows LDS-staged.
template<int CH>
__global__ __launch_bounds__(256) void scan_part1(
    const unsigned short* __restrict__ delta, const unsigned short* __restrict__ xc,
    const float* __restrict__ bc, const float* __restrict__ A_log,
    float* __restrict__ part_h, float* __restrict__ part_s, int L, int NCr)
{
    __shared__ float bcs[CH * 16];
    int tid = threadIdx.x;
    int dblk = blockIdx.x & 3;
    int rest = blockIdx.x >> 2;
    int c    = rest % NCr;
    int b    = rest / NCr;
    if (c == NCr - 1) return;          // dead partial (combine tail unused)
    int l0 = c * CH;
    for (int i = tid; i < CH * 16; i += 256) {
        int lr = i >> 4, s = i & 15;
        bcs[i] = bc[((size_t)b * L + l0 + lr) * 32 + s];
    }
    __syncthreads();
    int d    = dblk * 256 + tid;
    float A2[DSN];
    {
        const float4* ap = (const float4*)(A_log + d * DSN);
        #pragma unroll
        for (int q = 0; q < 4; q++) {
            float4 a4 = ap[q];
            A2[q*4+0] = -__expf(a4.x) * L2E;
            A2[q*4+1] = -__expf(a4.y) * L2E;
            A2[q*4+2] = -__expf(a4.z) * L2E;
            A2[q*4+3] = -__expf(a4.w) * L2E;
        }
    }
    float h[DSN];
    #pragma unroll
    for (int s = 0; s < DSN; s++) h[s] = 0.f;
    float ssum = 0.f;
    size_t rb = (size_t)b * L + l0;
    constexpr int HH = CH / 2;
    #pragma unroll
    for (int hh = 0; hh < 2; hh++) {
        unsigned short dls[HH], uss[HH];
        #pragma unroll
        for (int i = 0; i < HH; i++) {
            size_t rn = rb + hh * HH + i;
            dls[i] = delta[rn * DI + d];
            uss[i] = xc[rn * DI + d];
        }
        #pragma unroll
        for (int i = 0; i < HH; i++) {
            int st = hh * HH + i;
            float cdl = b2f(dls[i]), cu = b2f(uss[i]);
            const float* Bm = bcs + st * 16;
            float du = cdl * cu;
            ssum += cdl;
            #pragma unroll
            for (int s = 0; s < DSN; s++)
                h[s] = fmaf(fexp2(cdl * A2[s]), h[s], du * Bm[s]);
        }
    }
    // transposed store: [b][c][s][d] -> 16 coalesced 4B stores
    size_t base = ((size_t)(b * NCr + c) * DSN) * DI + d;
    #pragma unroll
    for (int s = 0; s < DSN; s++)
        part_h[base + (size_t)s * DI] = h[s];
    part_s[(size_t)(b * NCr + c) * DI + d] = ssum;
}

// combine over (b,s,d): lanes over d (coalesced). Prefix write-back only for
// chunks >= cwrite (part2 never reads the rest).
__global__ __launch_bounds__(256) void scan_combine(
    const float* __restrict__ A_log,
    float* __restrict__ part_h, const float* __restrict__ part_s, int NCr, int cwrite)
{
    int idx = blockIdx.x * 256 + threadIdx.x;   // b*16384 + s*1024 + d
    int d  = idx & (DI - 1);
    int s  = (idx >> 10) & (DSN - 1);
    int b  = idx >> 14;
    float A2 = -__expf(A_log[d * DSN + s]) * L2E;
    float h = 0.f;
    size_t sbase = (size_t)b * NCr * DI + d;
    size_t hbase = ((size_t)b * NCr * DSN + s) * DI + d;
    for (int c = 0; c < NCr; c++) {
        float ph = part_h[hbase];
        float S  = part_s[sbase];
        if (c >= cwrite) part_h[hbase] = h;
        h = fmaf(fexp2(A2 * S), h, ph);
        hbase += (size_t)DSN * DI;
        sbase += DI;
    }
}

// c0/lmin restrict output production — chunks < c0 skipped (out rows never
// consumed); within first processed chunk, rows l < lmin run the recurrence
// but skip the silu/store.
template<int CH>
__global__ __launch_bounds__(256) void scan_part2(
    const unsigned short* __restrict__ delta, const unsigned short* __restrict__ xc,
    const float* __restrict__ bc, const unsigned short* __restrict__ xz,
    const float* __restrict__ A_log, const float* __restrict__ Dv,
    const float* __restrict__ part_h,
    unsigned short* __restrict__ out, int L, int NCr, int c0, int lmin)
{
    __shared__ float bcs[CH * 32];
    int tid = threadIdx.x;
    int dblk = blockIdx.x & 3;
    int rest = blockIdx.x >> 2;
    int ncp  = NCr - c0;
    int c    = c0 + rest % ncp;
    int b    = rest / ncp;
    int l0 = c * CH;
    for (int i = tid; i < CH * 32; i += 256)
        bcs[i] = bc[((size_t)b * L + l0) * 32 + i];
    __syncthreads();
    int d    = dblk * 256 + tid;
    float A2[DSN];
    {
        const float4* ap = (const float4*)(A_log + d * DSN);
        #pragma unroll
        for (int q = 0; q < 4; q++) {
            float4 a4 = ap[q];
            A2[q*4+0] = -__expf(a4.x) * L2E;
            A2[q*4+1] = -__expf(a4.y) * L2E;
            A2[q*4+2] = -__expf(a4.z) * L2E;
            A2[q*4+3] = -__expf(a4.w) * L2E;
        }
    }
    float Dvd = Dv[d];
    // transposed load: [b][c][s][d] -> 16 coalesced 4B loads
    size_t hb = ((size_t)(b * NCr + c) * DSN) * DI + d;
    float h[DSN];
    #pragma unroll
    for (int s = 0; s < DSN; s++) h[s] = part_h[hb + (size_t)s * DI];
    size_t rb = (size_t)b * L + l0;
    constexpr int HH = CH / 2;
    #pragma unroll
    for (int hh = 0; hh < 2; hh++) {
        unsigned short dls[HH], uss[HH], zs[HH];
        #pragma unroll
        for (int i = 0; i < HH; i++) {
            size_t rn = rb + hh * HH + i;
            dls[i] = delta[rn * DI + d];
            uss[i] = xc[rn * DI + d];
            zs[i]  = xz[rn * 2048 + DI + d];
        }
        #pragma unroll
        for (int i = 0; i < HH; i++) {
            int st = hh * HH + i;
            float cdl = b2f(dls[i]), cu = b2f(uss[i]);
            const float* Bm = bcs + st * 32;
            const float* Cm = Bm + DSN;
            float du = cdl * cu;
            float y = 0.f;
            #pragma unroll
            for (int s = 0; s < DSN; s++) {
                h[s] = fmaf(fexp2(cdl * A2[s]), h[s], du * Bm[s]);
                y = fmaf(h[s], Cm[s], y);
            }
            if (l0 + st >= lmin) {   // wave-uniform branch
                float cz = b2f(zs[i]);
                float sil = cz * frcp(1.f + __expf(-cz));
                out[(rb + st) * DI + d] = f2b((y + cu * Dvd) * sil);
            }
        }
    }
}

// ================= residual add + LayerNorm; a + bsrc + sum(parts); fp32/bf16 outs
__global__ __launch_bounds__(128) void addln_kernel(
    const float* __restrict__ a, int amb, int absd, int aro, int lda,
    const float* __restrict__ bsrc, const float* __restrict__ parts, int nparts, int pstr,
    const float* __restrict__ g, const float* __restrict__ be,
    float* __restrict__ outf, int omb, int obsd, int oro, int ldo,
    unsigned short* __restrict__ outb, int bmb, int bbsd, int bro, int ldb)
{
    int m = blockIdx.x, t = threadIdx.x;
    int ar = map_row(m, amb, absd, aro);
    float4 x4 = ((const float4*)(a + (size_t)ar * lda))[t];
    float4 y4 = ((const float4*)(bsrc + (size_t)m * DM))[t];
    float v[4] = {x4.x + y4.x, x4.y + y4.y, x4.z + y4.z, x4.w + y4.w};
    for (int p = 0; p < nparts; p++) {
        float4 z4 = ((const float4*)(parts + (size_t)p * pstr + (size_t)m * DM))[t];
        v[0] += z4.x; v[1] += z4.y; v[2] += z4.z; v[3] += z4.w;
    }
    float sum = v[0] + v[1] + v[2] + v[3];
    float sq  = v[0]*v[0] + v[1]*v[1] + v[2]*v[2] + v[3]*v[3];
    #pragma unroll
    for (int o = 32; o > 0; o >>= 1) {
        sum += __shfl_down(sum, o);
        sq  += __shfl_down(sq, o);
    }
    __shared__ float s0[2], s1[2];
    if ((t & 63) == 0) { s0[t >> 6] = sum; s1[t >> 6] = sq; }
    __syncthreads();
    float tot = s0[0] + s0[1];
    float tsq = s1[0] + s1[1];
    float mu = tot * (1.f / DM);
    float var = tsq * (1.f / DM) - mu * mu;
    float rs = rsqrtf(var + 1e-6f);
    float4 g4 = ((const float4*)g)[t];
    float4 b4 = ((const float4*)be)[t];
    float o0 = (v[0] - mu) * rs * g4.x + b4.x;
    float o1 = (v[1] - mu) * rs * g4.y + b4.y;
    float o2 = (v[2] - mu) * rs * g4.z + b4.z;
    float o3 = (v[3] - mu) * rs * g4.w + b4.w;
    if (outf) {
        int orow = map_row(m, omb, obsd, oro);
        ((float4*)(outf + (size_t)orow * ldo))[t] = make_float4(o0, o1, o2, o3);
    }
    if (outb) {
        int brow = map_row(m, bmb, bbsd, bro);
        ((ushort4*)(outb + (size_t)brow * ldb))[t] =
            make_ushort4(f2b(o0), f2b(o1), f2b(o2), f2b(o3));
    }
}

static void run_scan(const unsigned short* dltb, const unsigned short* xcb, const float* bc,
                     const unsigned short* xzb, const float* A_log, const float* Dv,
                     float* part_h, float* part_s, unsigned short* out, int L, int NCr,
                     int c0, int lmin, hipStream_t stream)
{
    int blocks1 = BB * NCr * (DI / 256);
    int blocks2 = BB * (NCr - c0) * (DI / 256);
    if (L == SS) {
        scan_part1<8><<<blocks1, 256, 0, stream>>>(dltb, xcb, bc, A_log, part_h, part_s, L, NCr);
        scan_combine<<<BB * DI * DSN / 256, 256, 0, stream>>>(A_log, part_h, part_s, NCr, c0);
        scan_part2<8><<<blocks2, 256, 0, stream>>>(dltb, xcb, bc, xzb, A_log, Dv, part_h, out, L, NCr, c0, lmin);
    } else {
        scan_part1<24><<<blocks1, 256, 0, stream>>>(dltb, xcb, bc, A_log, part_h, part_s, L, NCr);
        scan_combine<<<BB * DI * DSN / 256, 256, 0, stream>>>(A_log, part_h, part_s, NCr, c0);
        scan_part2<24><<<blocks2, 256, 0, stream>>>(dltb, xcb, bc, xzb, A_log, Dv, part_h, out, L, NCr, c0, lmin);
    }
}

extern "C" void kernel_launch(void* const* d_in, const int* in_sizes, int n_in,
                              void* d_out, int out_size, void* d_ws, size_t ws_size,
                              hipStream_t stream)
{
    const float* tgt       = (const float*)d_in[0];
    const float* memory    = (const float*)d_in[1];
    const float* s_in_w    = (const float*)d_in[2];
    const float* s_conv_w  = (const float*)d_in[3];
    const float* s_conv_b  = (const float*)d_in[4];
    const float* s_xproj_w = (const float*)d_in[5];
    const float* s_dt_w    = (const float*)d_in[6];
    const float* s_dt_b    = (const float*)d_in[7];
    const float* s_A_log   = (const float*)d_in[8];
    const float* s_D_vec   = (const float*)d_in[9];
    const float* s_out_w   = (const float*)d_in[10];
    const float* c_in_w    = (const float*)d_in[11];
    const float* c_conv_w  = (const float*)d_in[12];
    const float* c_conv_b  = (const float*)d_in[13];
    const float* c_xproj_w = (const float*)d_in[14];
    const float* c_dt_w    = (const float*)d_in[15];
    const float* c_dt_b    = (const float*)d_in[16];
    const float* c_A_log   = (const float*)d_in[17];
    const float* c_D_vec   = (const float*)d_in[18];
    const float* c_out_w   = (const float*)d_in[19];
    const float* ln1_g     = (const float*)d_in[20];
    const float* ln1_b     = (const float*)d_in[21];
    const float* ln2_g     = (const float*)d_in[22];
    const float* ln2_b     = (const float*)d_in[23];
    const float* ln3_g     = (const float*)d_in[24];
    const float* ln3_b     = (const float*)d_in[25];
    const float* ffn_w1    = (const float*)d_in[26];
    const float* ffn_b1    = (const float*)d_in[27];
    const float* ffn_w2    = (const float*)d_in[28];
    const float* ffn_b2    = (const float*)d_in[29];
    float* outp = (float*)d_out;

    // ---- workspace layout ----
    float* ws     = (float*)d_ws;
    float* bc     = ws;                     // 393216  (12288 x 32: B|C)
    float* t1     = bc     + 393216;        // 2097152
    float* tbuf   = t1     + 2097152;       // 2097152
    float* part_h = tbuf   + 2097152;       // region 8388608 (B*64*DSN*DI, [b][c][s][d])
    float* proj   = part_h;                 // alias: 2097152 (dead during scans)
    float* pparts = part_h + 2097152;       // alias: 3 x 2097152 split-K partials
    float* pxd    = part_h;                 // alias: XDBL split-K partials (Z*M*64 <= 3.15M)
    float* part_s = part_h + 8388608;       // 524288  (B*64*DI)
    unsigned short* ub      = (unsigned short*)(part_s + 524288);
    unsigned short* dltb    = ub;                   // 12582912 (bf16 delta; ffnout aliases)
    unsigned short* catb    = dltb    + 12582912;   // 6291456 (dead after cross in-proj)
    unsigned short* tgtb    = catb    + 6291456;    // 2097152
    unsigned short* xzb     = tgtb    + 2097152;    // 25165824 (also fbuf alias)
    unsigned short* xcb     = xzb     + 25165824;   // 12582912
    unsigned short* ygb     = xcb     + 12582912;   // 12582912
    unsigned short* tbbf    = ygb     + 12582912;   // 2097152
    unsigned short* s_in_wb = tbbf    + 2097152;    // 1048576  (6-weight block, contiguous)
    unsigned short* c_in_wb = s_in_wb + 1048576;    // 1048576
    unsigned short* s_out_wb= c_in_wb + 1048576;    // 524288
    unsigned short* c_out_wb= s_out_wb+ 524288;     // 524288
    unsigned short* w1b     = c_out_wb+ 524288;     // 1048576
    unsigned short* w2b     = w1b     + 1048576;    // 1048576
    unsigned short* xprojb_s= w2b     + 1048576;    // 131072 (128 x 1024, padded)
    unsigned short* xprojb_c= xprojb_s+ 131072;     // 131072
    unsigned short* dtwb_s  = xprojb_c+ 131072;     // 65536  (1024 x 64, padded)
    unsigned short* dtwb_c  = dtwb_s  + 65536;      // 65536
    unsigned short* dtb     = dtwb_c  + 65536;      // 786432 (12288 x 64: dt | zeros)
    unsigned short* fbuf    = xzb;                  // FFN hidden alias
    float* ffnout  = (float*)dltb;                  // alias (dltb dead after cross scan)
    float* fparts  = ffnout + 2097152;              // 3 partials (extends into dead catb)

    // ---- fused prologue ----
    {
        PrepPtrs pp;
        pp.tgt = tgt; pp.mem = memory;
        pp.w[0]=s_in_w; pp.w[1]=c_in_w; pp.w[2]=s_out_w; pp.w[3]=c_out_w; pp.w[4]=ffn_w1; pp.w[5]=ffn_w2;
        pp.xpj_s = s_xproj_w; pp.xpj_c = c_xproj_w;
        pp.dtw_s = s_dt_w;    pp.dtw_c = c_dt_w;
        pp.tgtb = tgtb; pp.catb = catb; pp.wb = s_in_wb;
        pp.xprojb_s = xprojb_s; pp.xprojb_c = xprojb_c;
        pp.dtwb_s = dtwb_s; pp.dtwb_c = dtwb_c;
        prep_kernel<<<11648, 256, 0, stream>>>(pp);
    }

    // ---- self mamba (L=512, M=4096) ----
    mgemm_pipe<<<dim3(2048/128, 4096/128), 512, 0, stream>>>(
        tgtb, 4096, 0, 0, s_in_wb, nullptr, xzb, 512, ACT_NONE,
        4096, 0, 0, 2048, 0,  0, 0,0,0, 0, 0,0,0, 0);
    conv_silu_kernel<<<(BB*(SS/CONV_R)*128 + 255)/256, 256, 0, stream>>>(
        xzb, s_conv_w, s_conv_b, xcb, SS, BB*(SS/CONV_R)*128);
    // delta path stage 1 (split-K x4): x_dbl partials -> pxd; combine -> dt bf16 + bc fp32
    mgemm_kernel<<<dim3(1, 4096/128, 4), 256, 0, stream>>>(
        xcb, 4096, 0, 0, xprojb_s, nullptr, nullptr, nullptr, pxd, nullptr, 128, 1024, ACT_XDBL,
        4096, 0, 0, 0, 0, 0,  0, 0,0,0, 0, 0,0,0, 0);
    xdbl_combine<<<4096*16/256, 256, 0, stream>>>(pxd, dtb, bc, 4096, 4);
    // delta path stage 2: delta = softplus(dt @ dt_w^T + dt_b), K=64 (one k-iter)
    mgemm_kernel<<<dim3(1024/128, 4096/128), 256, 0, stream>>>(
        dtb, 4096, 0, 0, dtwb_s, s_dt_b, nullptr, dltb, nullptr, nullptr, 1024, 64, ACT_DELTA,
        4096, 0, 0, 1024, 0, 0,  0, 0,0,0, 0, 0,0,0, 0);
    run_scan(dltb, xcb, bc, xzb, s_A_log, s_D_vec, part_h, part_s, ygb, SS, 64, 0, 0, stream);
    mgemm_kernel<<<dim3(512/128, 4096/128, 4), 256, 0, stream>>>(
        ygb, 4096, 0, 0, s_out_wb, nullptr, proj, nullptr, nullptr, pparts, 512, 1024, ACT_NONE,
        4096, 0, 0, 512, 0, 2097152,  0, 0,0,0, 0, 0,0,0, 0);
    addln_kernel<<<4096, 128, 0, stream>>>(
        tgt, 4096, 0, 0, DM, proj, pparts, 3, 2097152, ln1_g, ln1_b,
        t1, 4096, 0, 0, DM, catb, 512, 1536, 1024, DM);

    // ---- cross mamba (L=1536, M=12288) ----
    // merged x-half (by<96: all 12288 rows, W rows 0..1023 -> cols 0..1023) and
    // z-half (by>=96: tgt rows only, W rows 1024..2047 -> cols 1024..2047)
    mgemm_pipe<<<dim3(1024/128, 96 + 32), 512, 0, stream>>>(
        catb, 12288, 0, 0, c_in_wb, nullptr, xzb, 512, ACT_NONE,
        12288, 0, 0, 2048, 0,
        96, 512, 1536, 1024, 1024 * 512, 512, 1536, 1024, 1024);
    conv_silu_kernel<<<(BB*(LCAT/CONV_R)*128 + 255)/256, 256, 0, stream>>>(
        xzb, c_conv_w, c_conv_b, xcb, LCAT, BB*(LCAT/CONV_R)*128);
    mgemm_kernel<<<dim3(1, 12288/128, 4), 256, 0, stream>>>(
        xcb, 12288, 0, 0, xprojb_c, nullptr, nullptr, nullptr, pxd, nullptr, 128, 1024, ACT_XDBL,
        12288, 0, 0, 0, 0, 0,  0, 0,0,0, 0, 0,0,0, 0);
    xdbl_combine<<<12288*16/256, 256, 0, stream>>>(pxd, dtb, bc, 12288, 4);
    mgemm_kernel<<<dim3(1024/128, 12288/128), 256, 0, stream>>>(
        dtb, 12288, 0, 0, dtwb_c, c_dt_b, nullptr, dltb, nullptr, nullptr, 1024, 64, ACT_DELTA,
        12288, 0, 0, 1024, 0, 0,  0, 0,0,0, 0, 0,0,0, 0);
    // part2 restricted: CH=24, chunk 42 starts at row 1008 (<1024); lmin guards 1008..1023
    run_scan(dltb, xcb, bc, xzb, c_A_log, c_D_vec, part_h, part_s, ygb, LCAT, 64, 42, 1024, stream);
    mgemm_kernel<<<dim3(512/128, 4096/128, 4), 256, 0, stream>>>(
        ygb, 512, 1536, 1024, c_out_wb, nullptr, proj, nullptr, nullptr, pparts, 512, 1024, ACT_NONE,
        4096, 0, 0, 512, 0, 2097152,  0, 0,0,0, 0, 0,0,0, 0);
    addln_kernel<<<4096, 128, 0, stream>>>(
        t1, 4096, 0, 0, DM, proj, pparts, 3, 2097152, ln2_g, ln2_b,
        tbuf, 4096, 0, 0, DM, tbbf, 4096, 0, 0, DM);

    // ---- FFN ----
    mgemm_pipe<<<dim3(2048/128, 4096/128), 512, 0, stream>>>(
        tbbf, 4096, 0, 0, w1b, ffn_b1, fbuf, 512, ACT_RELU,
        4096, 0, 0, 2048, 0,  0, 0,0,0, 0, 0,0,0, 0);
    mgemm_kernel<<<dim3(512/128, 4096/128, 4), 256, 0, stream>>>(
        fbuf, 4096, 0, 0, w2b, ffn_b2, ffnout, nullptr, nullptr, fparts, 512, 2048, ACT_NONE,
        4096, 0, 0, 512, 0, 2097152,  0, 0,0,0, 0, 0,0,0, 0);
    addln_kernel<<<4096, 128, 0, stream>>>(
        tbuf, 4096, 0, 0, DM, ffnout, fparts, 3, 2097152, ln3_g, ln3_b,
        outp, 4096, 0, 0, DM, nullptr, 0, 0, 0, 0);
}

// Round 11
// 486.451 us; speedup vs baseline: 1.0170x; 1.0170x over previous
//
#include <hip/hip_runtime.h>
#include <math.h>

// Problem constants
#define DM    512
#define DI    1024
#define DSN   16
#define DTR   32
#define DFFN  2048
#define BB    8
#define SS    512
#define TTM   1024
#define LCAT  1536
#define CONV_R 8      // rows per conv thread (weight-load amortization)

#define ACT_NONE     0
#define ACT_RELU     1
#define ACT_DELTA    3   // softplus+bias -> Cb(delta bf16, stride 1024)
#define ACT_XDBL     4   // fp32 partials (n<64) -> C2[(z*M+m)*64+n]; combined later

typedef __attribute__((ext_vector_type(8))) short short8;
typedef __attribute__((ext_vector_type(8))) unsigned short ushort8;
typedef __attribute__((ext_vector_type(4))) float f32x4;

#define L2E 1.4426950408889634f

__device__ __forceinline__ unsigned short f2b(float f) {
    unsigned int u = __float_as_uint(f);
    return (unsigned short)((u + 0x7FFFu + ((u >> 16) & 1u)) >> 16);
}
__device__ __forceinline__ float b2f(unsigned short h) {
    return __uint_as_float(((unsigned int)h) << 16);
}
__device__ __forceinline__ float fast_softplus(float v) {
    return (v > 20.f) ? v : __logf(1.f + __expf(v));
}
__device__ __forceinline__ float fexp2(float x) {
#if __has_builtin(__builtin_amdgcn_exp2f)
    return __builtin_amdgcn_exp2f(x);
#else
    float r; asm("v_exp_f32 %0, %1" : "=v"(r) : "v"(x)); return r;
#endif
}
__device__ __forceinline__ float frcp(float x) {
    return __builtin_amdgcn_rcpf(x);
}
__device__ __forceinline__ void gld16(const void* g, void* l) {
    __builtin_amdgcn_global_load_lds(
        (const __attribute__((address_space(1))) void*)g,
        (__attribute__((address_space(3))) void*)l, 16, 0, 0);
}

__device__ __forceinline__ int map_row(int m, int mb, int bs, int ro) {
    int q = m / mb;
    return q * bs + ro + (m - q * mb);
}

// ================= bf16 MFMA GEMM: C[row(m),n] = act(A[row(m),k] * W[n,k] + bias[n])
// Tile 128x128, BK=64. Full 3-bit XOR LDS swizzle (bank-conflict-free b128 reads).
// Scalar three-branch epilogue. ysplit merges two sub-problems in one grid.
// Split-K via gridDim.z: z>0 writes fp32 partials to Cf2 + (z-1)*pstr
// (ACT_NONE) or C2[(z*M+m)*64+n] (ACT_XDBL).
__global__ __launch_bounds__(256) void mgemm_kernel(
    const unsigned short* __restrict__ A, int mb, int bs, int ro,
    const unsigned short* __restrict__ W, const float* __restrict__ bias,
    float* __restrict__ Cf, unsigned short* __restrict__ Cb,
    float* __restrict__ C2, float* __restrict__ Cf2,
    int N, int K, int act,
    int omb, int obs, int oro, int ldc, int nofs, int pstr,
    int ysplit, int amb2, int abs2, int aro2, int wofs2,
    int omb2, int obs2, int oro2, int nofs2)
{
    __shared__ __align__(16) unsigned short As[128 * 64];
    __shared__ __align__(16) unsigned short Bs[128 * 64];
    int tid = threadIdx.x;
    int lane = tid & 63, wave = tid >> 6;
    int wy = wave >> 1, wx = wave & 1;
    int bx = blockIdx.x, by = blockIdx.y;
    int nx = gridDim.x, ny = gridDim.y;
    const unsigned short* Wp = W;
    if (ysplit) {
        if (by >= ysplit) {
            by -= ysplit; ny = gridDim.y - ysplit;
            mb = amb2; bs = abs2; ro = aro2; Wp += wofs2;
            omb = omb2; obs = obs2; oro = oro2; nofs = nofs2;
        } else ny = ysplit;
    }
    // XCD-band swizzle over (bx,by) within the (sub-)grid; z reuses mapping
    int f = by * nx + bx;
    int xcd = f & 7, j2 = f >> 3;
    int bandh = ny >> 3;
    int m0 = (xcd * bandh + j2 / nx) * 128;
    int n0 = (j2 % nx) * 128;
    // split-K
    int Kh = K / gridDim.z;
    int kbeg = blockIdx.z * Kh, kend = kbeg + Kh;
    float* Cfo = Cf;
    const float* biaso = bias;
    if (blockIdx.z) { Cfo = Cf2 + (size_t)(blockIdx.z - 1) * pstr; biaso = nullptr; }

    // staging: wave stages chunk positions c = wave*256 + j*64 + lane (j=0..3)
    unsigned aoff[4], boff[4];
    unsigned short* la[4];
    unsigned short* lb[4];
    #pragma unroll
    for (int j = 0; j < 4; j++) {
        int c  = wave * 256 + j * 64 + lane;
        int r  = c >> 3;                    // tile row 0..127
        int q  = c & 7;
        int g  = q ^ (r & 7);               // un-swizzled k-chunk 0..7 (3-bit XOR)
        int arow = map_row(m0 + r, mb, bs, ro);
        aoff[j] = (unsigned)(arow * K + g * 8);
        boff[j] = (unsigned)((n0 + r) * K + g * 8);
        la[j] = As + (size_t)(wave * 256 + j * 64) * 8;   // chunk pos * 8 shorts
        lb[j] = Bs + (size_t)(wave * 256 + j * 64) * 8;
    }
    // fragment read bases; R&7 == fm&7 (wy*64, t*16 are multiples of 8/16)
    int fm = lane & 15, fg = lane >> 4;
    int sw = fg ^ (fm & 3);
    int b2 = (fm >> 2) & 1;
    const unsigned short* arp = As + ((size_t)(wy * 64 + fm) * 8 + sw) * 8;
    const unsigned short* brp = Bs + ((size_t)(wx * 64 + fm) * 8 + sw) * 8;

    f32x4 acc[4][4];
    #pragma unroll
    for (int i = 0; i < 4; i++)
        #pragma unroll
        for (int j = 0; j < 4; j++) acc[i][j] = 0.f;

    for (int k0 = kbeg; k0 < kend; k0 += 64) {
        #pragma unroll
        for (int j = 0; j < 4; j++) {
            gld16(A  + aoff[j] + k0, la[j]);
            gld16(Wp + boff[j] + k0, lb[j]);
        }
        __syncthreads();
        #pragma unroll
        for (int h = 0; h < 2; h++) {
            int ho = ((h ^ b2) * 32);
            short8 af[4], bfr[4];
            #pragma unroll
            for (int t = 0; t < 4; t++) af[t]  = *(const short8*)(arp + ho + t * 1024);
            #pragma unroll
            for (int t = 0; t < 4; t++) bfr[t] = *(const short8*)(brp + ho + t * 1024);
            #pragma unroll
            for (int i = 0; i < 4; i++)
                #pragma unroll
                for (int j = 0; j < 4; j++)
                    acc[i][j] = __builtin_amdgcn_mfma_f32_16x16x32_bf16(af[i], bfr[j], acc[i][j], 0, 0, 0);
        }
        __syncthreads();
    }

    // epilogue: C/D layout col=lane&15 (n), row=(lane>>4)*4+reg (m)
    int en = lane & 15, em = (lane >> 4) * 4;
    if (act == ACT_XDBL) {
        size_t zb = (size_t)blockIdx.z * omb;
        #pragma unroll
        for (int j = 0; j < 4; j++) {
            int n = n0 + wx * 64 + j * 16 + en;
            if (n >= 64) continue;
            #pragma unroll
            for (int i = 0; i < 4; i++) {
                int mbase = m0 + wy * 64 + i * 16 + em;
                #pragma unroll
                for (int r = 0; r < 4; r++)
                    C2[(zb + mbase + r) * 64 + n] = acc[i][j][r];
            }
        }
        return;
    }
    if (act == ACT_DELTA) {
        #pragma unroll
        for (int j = 0; j < 4; j++) {
            int n = n0 + wx * 64 + j * 16 + en;
            float bv = bias[n];
            #pragma unroll
            for (int i = 0; i < 4; i++) {
                int mbase = m0 + wy * 64 + i * 16 + em;
                #pragma unroll
                for (int r = 0; r < 4; r++) {
                    float v = acc[i][j][r] + bv;
                    Cb[(size_t)(mbase + r) * 1024 + n] = f2b(fast_softplus(v));
                }
            }
        }
        return;
    }
    #pragma unroll
    for (int j = 0; j < 4; j++) {
        int n = n0 + wx * 64 + j * 16 + en;
        float bv = biaso ? biaso[n] : 0.f;
        #pragma unroll
        for (int i = 0; i < 4; i++) {
            int mbase = m0 + wy * 64 + i * 16 + em;
            #pragma unroll
            for (int r = 0; r < 4; r++) {
                float v = acc[i][j][r] + bv;
                if (act == ACT_RELU) v = v > 0.f ? v : 0.f;
                int orow = map_row(mbase + r, omb, obs, oro);
                size_t off = (size_t)orow * ldc + nofs + n;
                if (Cb) Cb[off] = f2b(v);
                else    Cfo[off] = v;
            }
        }
    }
}

// ================= counted-vmcnt 2-deep pipelined GEMM (T3/T4 minimum)
// R21: used ONLY for the cross in-proj (1024-block grid, 2 full CU rounds —
// the pipe won there: 48.5 -> <=41 us). On 512-block grids (self in-proj,
// FFN1) it REGRESSED vs mgemm_kernel (2 lockstep blocks/CU lack cross-block
// overlap for prologue/epilogue bubbles) — those stay on mgemm_kernel.
__global__ __launch_bounds__(512, 4) void mgemm_pipe(
    const unsigned short* __restrict__ A, int mb, int bs, int ro,
    const unsigned short* __restrict__ W, const float* __restrict__ bias,
    unsigned short* __restrict__ Cb, int K, int act,
    int omb, int obs, int oro, int ldc, int nofs,
    int ysplit, int amb2, int abs2, int aro2, int wofs2,
    int omb2, int obs2, int oro2, int nofs2)
{
    __shared__ __align__(16) unsigned short smem[32768];   // 2 x (A 16KB | B 16KB)
    int tid = threadIdx.x;
    int lane = tid & 63, wave = tid >> 6;
    int wy = wave >> 2, wx = wave & 3;       // 2x4 wave grid: 64x32 out per wave
    int bx = blockIdx.x, by = blockIdx.y;
    int nx = gridDim.x, ny = gridDim.y;
    const unsigned short* Wp = W;
    if (ysplit) {
        if (by >= ysplit) {
            by -= ysplit; ny = gridDim.y - ysplit;
            mb = amb2; bs = abs2; ro = aro2; Wp += wofs2;
            omb = omb2; obs = obs2; oro = oro2; nofs = nofs2;
        } else ny = ysplit;
    }
    int f = by * nx + bx;
    int xcd = f & 7, j2 = f >> 3;
    int bandh = ny >> 3;
    int m0 = (xcd * bandh + j2 / nx) * 128;
    int n0 = (j2 % nx) * 128;

    // staging: 2 chunk-positions per thread per operand (1024 positions total)
    int c0 = tid, c1 = tid + 512;
    int r0 = c0 >> 3, g0 = (c0 & 7) ^ (r0 & 7);
    int r1 = c1 >> 3, g1 = (c1 & 7) ^ (r1 & 7);
    unsigned ga0 = (unsigned)(map_row(m0 + r0, mb, bs, ro) * K + g0 * 8);
    unsigned ga1 = (unsigned)(map_row(m0 + r1, mb, bs, ro) * K + g1 * 8);
    unsigned gb0 = (unsigned)((n0 + r0) * K + g0 * 8);
    unsigned gb1 = (unsigned)((n0 + r1) * K + g1 * 8);
    // wave-uniform LDS bases (shorts); HW adds lane*16B
    int uA0 = wave * 512, uA1 = wave * 512 + 4096;
    int uB0 = 8192 + wave * 512, uB1 = 8192 + 4096 + wave * 512;

#define PSTAGE(kk, bofs) do { \
    gld16(A  + ga0 + (kk), smem + (bofs) + uA0); \
    gld16(Wp + gb0 + (kk), smem + (bofs) + uB0); \
    gld16(A  + ga1 + (kk), smem + (bofs) + uA1); \
    gld16(Wp + gb1 + (kk), smem + (bofs) + uB1); \
} while (0)

    int fm = lane & 15, fg = lane >> 4;
    int sw = fg ^ (fm & 3);
    int b2 = (fm >> 2) & 1;
    int arpO = (wy * 64 + fm) * 64 + sw * 8;          // shorts, A region
    int brpO = 8192 + (wx * 32 + fm) * 64 + sw * 8;   // shorts, B region

    f32x4 acc[4][2];
    #pragma unroll
    for (int i = 0; i < 4; i++)
        #pragma unroll
        for (int j = 0; j < 2; j++) acc[i][j] = 0.f;

    int nk = K >> 6;
    PSTAGE(0, 0);          // stage 0 -> buf0
    PSTAGE(64, 16384);     // stage 1 -> buf1  (8 loads outstanding)

    for (int t = 0; t < nk; ++t) {
        if (t + 1 < nk) { asm volatile("s_waitcnt vmcnt(4)" ::: "memory"); }
        else            { asm volatile("s_waitcnt vmcnt(0)" ::: "memory"); }
        __builtin_amdgcn_s_barrier();            // stage t visible block-wide
        __builtin_amdgcn_sched_barrier(0);
        int bo = (t & 1) << 14;                  // buffer offset in shorts
        short8 af[2][4], bfr[2][2];
        #pragma unroll
        for (int h = 0; h < 2; h++) {
            int ho = ((h ^ b2) << 5);
            #pragma unroll
            for (int i = 0; i < 4; i++)
                af[h][i] = *(const short8*)(smem + bo + arpO + ho + i * 1024);
            #pragma unroll
            for (int j = 0; j < 2; j++)
                bfr[h][j] = *(const short8*)(smem + bo + brpO + ho + j * 1024);
        }
        asm volatile("s_waitcnt lgkmcnt(0)" ::: "memory");
        __builtin_amdgcn_sched_barrier(0);
        __builtin_amdgcn_s_barrier();            // all waves done reading buf
        __builtin_amdgcn_sched_barrier(0);
        if (t + 2 < nk) PSTAGE((t + 2) * 64, bo);   // overwrite read-done buf
        #pragma unroll
        for (int h = 0; h < 2; h++)
            #pragma unroll
            for (int i = 0; i < 4; i++)
                #pragma unroll
                for (int j = 0; j < 2; j++)
                    acc[i][j] = __builtin_amdgcn_mfma_f32_16x16x32_bf16(
                        af[h][i], bfr[h][j], acc[i][j], 0, 0, 0);
    }
#undef PSTAGE

    // epilogue: col = n0 + wx*32 + j*16 + (lane&15); row = m0 + wy*64 + i*16 + (lane>>4)*4 + r
    int en = lane & 15, em = (lane >> 4) * 4;
    #pragma unroll
    for (int j = 0; j < 2; j++) {
        int n = n0 + wx * 32 + j * 16 + en;
        float bv = bias ? bias[n] : 0.f;
        #pragma unroll
        for (int i = 0; i < 4; i++) {
            int mbase = m0 + wy * 64 + i * 16 + em;
            #pragma unroll
            for (int r = 0; r < 4; r++) {
                float v = acc[i][j][r] + bv;
                if (act == ACT_RELU) v = v > 0.f ? v : 0.f;
                int orow = map_row(mbase + r, omb, obs, oro);
                Cb[(size_t)orow * ldc + nofs + n] = f2b(v);
            }
        }
    }
}

// ================= XDBL split-K combine: sum Z partials -> dt bf16 + bc fp32
__global__ __launch_bounds__(256) void xdbl_combine(
    const float* __restrict__ pxd, unsigned short* __restrict__ dtb,
    float* __restrict__ bcout, int M, int Z)
{
    int idx = blockIdx.x * 256 + threadIdx.x;     // m*16 + n4
    int m = idx >> 4, n4 = idx & 15;
    int n = n4 * 4;
    float4 s = make_float4(0.f, 0.f, 0.f, 0.f);
    for (int z = 0; z < Z; z++) {
        float4 p = *(const float4*)(pxd + ((size_t)z * M + m) * 64 + n);
        s.x += p.x; s.y += p.y; s.z += p.z; s.w += p.w;
    }
    if (n < 32) {
        ((ushort4*)(dtb + (size_t)m * 64))[n4] =
            make_ushort4(f2b(s.x), f2b(s.y), f2b(s.z), f2b(s.w));
    } else {
        *(float4*)(bcout + (size_t)m * 32 + (n - 32)) = s;
        ((ushort4*)(dtb + (size_t)m * 64))[n4] = make_ushort4(0, 0, 0, 0);  // zero dt pad
    }
}

// ================= fused prologue: all fp32->bf16 converts + padded weight fills
struct PrepPtrs {
    const float* tgt; const float* mem;
    const float* w[6];
    const float* xpj_s; const float* xpj_c;
    const float* dtw_s; const float* dtw_c;
    unsigned short* tgtb; unsigned short* catb; unsigned short* wb;
    unsigned short* xprojb_s; unsigned short* xprojb_c;
    unsigned short* dtwb_s; unsigned short* dtwb_c;
};
__global__ __launch_bounds__(256) void prep_kernel(PrepPtrs p)
{
    int u = blockIdx.x * 256 + threadIdx.x;
    if (u < 524288) {
        float4 v = ((const float4*)p.tgt)[u];
        ((ushort4*)p.tgtb)[u] = make_ushort4(f2b(v.x), f2b(v.y), f2b(v.z), f2b(v.w));
        return;
    }
    if (u < 1572864) {
        int f = u - 524288;
        int b = f >> 17, rem = f & 131071;          // per_b = 131072
        float4 v = ((const float4*)p.mem)[f];
        ((ushort4*)p.catb)[(size_t)b * 196608 + rem] =
            make_ushort4(f2b(v.x), f2b(v.y), f2b(v.z), f2b(v.w));
        return;
    }
    if (u < 2883584) {
        const int cum[7] = {0, 262144, 524288, 655360, 786432, 1048576, 1310720};
        int i = u - 1572864;
        int seg = 0;
        #pragma unroll
        for (int s = 1; s < 6; s++) seg += (i >= cum[s]);
        float4 v = ((const float4*)p.w[seg])[i - cum[seg]];
        ((ushort4*)p.wb)[i] = make_ushort4(f2b(v.x), f2b(v.y), f2b(v.z), f2b(v.w));
        return;
    }
    if (u < 2949120) {
        int i = u - 2883584;
        const float* src = p.xpj_s;
        unsigned short* dst = p.xprojb_s;
        if (i >= 32768) { i -= 32768; src = p.xpj_c; dst = p.xprojb_c; }
        int n = i >> 8;                             // out row (of 128)
        ushort4 o = make_ushort4(0, 0, 0, 0);
        if (n < 64) {
            float4 v = ((const float4*)src)[i];
            o = make_ushort4(f2b(v.x), f2b(v.y), f2b(v.z), f2b(v.w));
        }
        ((ushort4*)dst)[i] = o;
        return;
    }
    {
        int i = u - 2949120;
        const float* src = p.dtw_s;
        unsigned short* dst = p.dtwb_s;
        if (i >= 16384) { i -= 16384; src = p.dtw_c; dst = p.dtwb_c; }
        int n = i >> 4, c = (i & 15) * 4;
        ushort4 o = make_ushort4(0, 0, 0, 0);
        if (c < 32) {
            float4 v = *(const float4*)(src + n * 32 + c);
            o = make_ushort4(f2b(v.x), f2b(v.y), f2b(v.z), f2b(v.w));
        }
        ((ushort4*)dst)[i] = o;
    }
}

// ================= Depthwise causal conv (width 4) + bias + SiLU
__global__ __launch_bounds__(256) void conv_silu_kernel(
    const unsigned short* __restrict__ xz,
    const float* __restrict__ cw,
    const float* __restrict__ cb,
    unsigned short* __restrict__ xc, int L, int total)
{
    int idx = blockIdx.x * blockDim.x + threadIdx.x;
    if (idx >= total) return;
    int d8 = idx & 127;
    int d0 = d8 * 8;
    int t  = idx >> 7;                 // b*(L/CONV_R) + lq
    int nq = L / CONV_R;
    int b  = t / nq;
    int l0 = (t - b * nq) * CONV_R;
    size_t rbase = (size_t)b * L + l0;

    float4 wv[8];
    #pragma unroll
    for (int j = 0; j < 8; j++) wv[j] = *(const float4*)(cw + (d0 + j) * 4);
    float bias[8];
    {
        float4 c0 = ((const float4*)(cb + d0))[0];
        float4 c1 = ((const float4*)(cb + d0))[1];
        bias[0]=c0.x; bias[1]=c0.y; bias[2]=c0.z; bias[3]=c0.w;
        bias[4]=c1.x; bias[5]=c1.y; bias[6]=c1.z; bias[7]=c1.w;
    }
    ushort8 win[CONV_R + 3];
    #pragma unroll
    for (int k = 0; k < 3; k++) {
        ushort8 z;
        #pragma unroll
        for (int j = 0; j < 8; j++) z[j] = 0;
        win[k] = (l0 - 3 + k >= 0)
            ? *(const ushort8*)(xz + (rbase - 3 + k) * 2048 + d0) : z;
    }
    #pragma unroll
    for (int i = 0; i < CONV_R; i++)
        win[3 + i] = *(const ushort8*)(xz + (rbase + i) * 2048 + d0);

    const float* w = (const float*)&wv[0];
    #pragma unroll
    for (int i = 0; i < CONV_R; i++) {
        float acc[8];
        #pragma unroll
        for (int j = 0; j < 8; j++) acc[j] = bias[j];
        #pragma unroll
        for (int k = 0; k < 4; k++) {
            ushort8 v = win[i + k];
            #pragma unroll
            for (int j = 0; j < 8; j++)
                acc[j] = fmaf(b2f(v[j]), w[j * 4 + k], acc[j]);
        }
        ushort8 o;
        #pragma unroll
        for (int j = 0; j < 8; j++)
            o[j] = f2b(acc[j] * frcp(1.f + __expf(-acc[j])));
        *(ushort8*)(xc + (rbase + i) * 1024 + d0) = o;
    }
}

// ================= Chunked selective scan (delta bf16), CH = compile-time rows
// part_h layout [b][c][s][d] (coalesced 4B lane-consecutive access).
// Full-chunk register preload in two halves; bc rows LDS-staged.
template<int CH>
__global__ __launch_bounds__(256) void scan_part1(
    const unsigned short* __restrict__ delta, const unsigned short* __restrict__ xc,
    const float* __restrict__ bc, const float* __restrict__ A_log,
    float* __restrict__ part_h, float* __restrict__ part_s, int L, int NCr)
{
    __shared__ float bcs[CH * 16];
    int tid = threadIdx.x;
    int dblk = blockIdx.x & 3;
    int rest = blockIdx.x >> 2;
    int c    = rest % NCr;
    int b    = rest / NCr;
    if (c == NCr - 1) return;          // dead partial (combine tail unused)
    int l0 = c * CH;
    for (int i = tid; i < CH * 16; i += 256) {
        int lr = i >> 4, s = i & 15;
        bcs[i] = bc[((size_t)b * L + l0 + lr) * 32 + s];
    }
    __syncthreads();
    int d    = dblk * 256 + tid;
    float A2[DSN];
    {
        const float4* ap = (const float4*)(A_log + d * DSN);
        #pragma unroll
        for (int q = 0; q < 4; q++) {
            float4 a4 = ap[q];
            A2[q*4+0] = -__expf(a4.x) * L2E;
            A2[q*4+1] = -__expf(a4.y) * L2E;
            A2[q*4+2] = -__expf(a4.z) * L2E;
            A2[q*4+3] = -__expf(a4.w) * L2E;
        }
    }
    float h[DSN];
    #pragma unroll
    for (int s = 0; s < DSN; s++) h[s] = 0.f;
    float ssum = 0.f;
    size_t rb = (size_t)b * L + l0;
    constexpr int HH = CH / 2;
    #pragma unroll
    for (int hh = 0; hh < 2; hh++) {
        unsigned short dls[HH], uss[HH];
        #pragma unroll
        for (int i = 0; i < HH; i++) {
            size_t rn = rb + hh * HH + i;
            dls[i] = delta[rn * DI + d];
            uss[i] = xc[rn * DI + d];
        }
        #pragma unroll
        for (int i = 0; i < HH; i++) {
            int st = hh * HH + i;
            float cdl = b2f(dls[i]), cu = b2f(uss[i]);
            const float* Bm = bcs + st * 16;
            float du = cdl * cu;
            ssum += cdl;
            #pragma unroll
            for (int s = 0; s < DSN; s++)
                h[s] = fmaf(fexp2(cdl * A2[s]), h[s], du * Bm[s]);
        }
    }
    // transposed store: [b][c][s][d] -> 16 coalesced 4B stores
    size_t base = ((size_t)(b * NCr + c) * DSN) * DI + d;
    #pragma unroll
    for (int s = 0; s < DSN; s++)
        part_h[base + (size_t)s * DI] = h[s];
    part_s[(size_t)(b * NCr + c) * DI + d] = ssum;
}

// combine over (b,s,d): lanes over d (coalesced). Prefix write-back only for
// chunks >= cwrite (part2 never reads the rest).
__global__ __launch_bounds__(256) void scan_combine(
    const float* __restrict__ A_log,
    float* __restrict__ part_h, const float* __restrict__ part_s, int NCr, int cwrite)
{
    int idx = blockIdx.x * 256 + threadIdx.x;   // b*16384 + s*1024 + d
    int d  = idx & (DI - 1);
    int s  = (idx >> 10) & (DSN - 1);
    int b  = idx >> 14;
    float A2 = -__expf(A_log[d * DSN + s]) * L2E;
    float h = 0.f;
    size_t sbase = (size_t)b * NCr * DI + d;
    size_t hbase = ((size_t)b * NCr * DSN + s) * DI + d;
    for (int c = 0; c < NCr; c++) {
        float ph = part_h[hbase];
        float S  = part_s[sbase];
        if (c >= cwrite) part_h[hbase] = h;
        h = fmaf(fexp2(A2 * S), h, ph);
        hbase += (size_t)DSN * DI;
        sbase += DI;
    }
}

// c0/lmin restrict output production — chunks < c0 skipped (out rows never
// consumed); within first processed chunk, rows l < lmin run the recurrence
// but skip the silu/store.
template<int CH>
__global__ __launch_bounds__(256) void scan_part2(
    const unsigned short* __restrict__ delta, const unsigned short* __restrict__ xc,
    const float* __restrict__ bc, const unsigned short* __restrict__ xz,
    const float* __restrict__ A_log, const float* __restrict__ Dv,
    const float* __restrict__ part_h,
    unsigned short* __restrict__ out, int L, int NCr, int c0, int lmin)
{
    __shared__ float bcs[CH * 32];
    int tid = threadIdx.x;
    int dblk = blockIdx.x & 3;
    int rest = blockIdx.x >> 2;
    int ncp  = NCr - c0;
    int c    = c0 + rest % ncp;
    int b    = rest / ncp;
    int l0 = c * CH;
    for (int i = tid; i < CH * 32; i += 256)
        bcs[i] = bc[((size_t)b * L + l0) * 32 + i];
    __syncthreads();
    int d    = dblk * 256 + tid;
    float A2[DSN];
    {
        const float4* ap = (const float4*)(A_log + d * DSN);
        #pragma unroll
        for (int q = 0; q < 4; q++) {
            float4 a4 = ap[q];
            A2[q*4+0] = -__expf(a4.x) * L2E;
            A2[q*4+1] = -__expf(a4.y) * L2E;
            A2[q*4+2] = -__expf(a4.z) * L2E;
            A2[q*4+3] = -__expf(a4.w) * L2E;
        }
    }
    float Dvd = Dv[d];
    // transposed load: [b][c][s][d] -> 16 coalesced 4B loads
    size_t hb = ((size_t)(b * NCr + c) * DSN) * DI + d;
    float h[DSN];
    #pragma unroll
    for (int s = 0; s < DSN; s++) h[s] = part_h[hb + (size_t)s * DI];
    size_t rb = (size_t)b * L + l0;
    constexpr int HH = CH / 2;
    #pragma unroll
    for (int hh = 0; hh < 2; hh++) {
        unsigned short dls[HH], uss[HH], zs[HH];
        #pragma unroll
        for (int i = 0; i < HH; i++) {
            size_t rn = rb + hh * HH + i;
            dls[i] = delta[rn * DI + d];
            uss[i] = xc[rn * DI + d];
            zs[i]  = xz[rn * 2048 + DI + d];
        }
        #pragma unroll
        for (int i = 0; i < HH; i++) {
            int st = hh * HH + i;
            float cdl = b2f(dls[i]), cu = b2f(uss[i]);
            const float* Bm = bcs + st * 32;
            const float* Cm = Bm + DSN;
            float du = cdl * cu;
            float y = 0.f;
            #pragma unroll
            for (int s = 0; s < DSN; s++) {
                h[s] = fmaf(fexp2(cdl * A2[s]), h[s], du * Bm[s]);
                y = fmaf(h[s], Cm[s], y);
            }
            if (l0 + st >= lmin) {   // wave-uniform branch
                float cz = b2f(zs[i]);
                float sil = cz * frcp(1.f + __expf(-cz));
                out[(rb + st) * DI + d] = f2b((y + cu * Dvd) * sil);
            }
        }
    }
}

// ================= residual add + LayerNorm; a + bsrc + sum(parts); fp32/bf16 outs
__global__ __launch_bounds__(128) void addln_kernel(
    const float* __restrict__ a, int amb, int absd, int aro, int lda,
    const float* __restrict__ bsrc, const float* __restrict__ parts, int nparts, int pstr,
    const float* __restrict__ g, const float* __restrict__ be,
    float* __restrict__ outf, int omb, int obsd, int oro, int ldo,
    unsigned short* __restrict__ outb, int bmb, int bbsd, int bro, int ldb)
{
    int m = blockIdx.x, t = threadIdx.x;
    int ar = map_row(m, amb, absd, aro);
    float4 x4 = ((const float4*)(a + (size_t)ar * lda))[t];
    float4 y4 = ((const float4*)(bsrc + (size_t)m * DM))[t];
    float v[4] = {x4.x + y4.x, x4.y + y4.y, x4.z + y4.z, x4.w + y4.w};
    for (int p = 0; p < nparts; p++) {
        float4 z4 = ((const float4*)(parts + (size_t)p * pstr + (size_t)m * DM))[t];
        v[0] += z4.x; v[1] += z4.y; v[2] += z4.z; v[3] += z4.w;
    }
    float sum = v[0] + v[1] + v[2] + v[3];
    float sq  = v[0]*v[0] + v[1]*v[1] + v[2]*v[2] + v[3]*v[3];
    #pragma unroll
    for (int o = 32; o > 0; o >>= 1) {
        sum += __shfl_down(sum, o);
        sq  += __shfl_down(sq, o);
    }
    __shared__ float s0[2], s1[2];
    if ((t & 63) == 0) { s0[t >> 6] = sum; s1[t >> 6] = sq; }
    __syncthreads();
    float tot = s0[0] + s0[1];
    float tsq = s1[0] + s1[1];
    float mu = tot * (1.f / DM);
    float var = tsq * (1.f / DM) - mu * mu;
    float rs = rsqrtf(var + 1e-6f);
    float4 g4 = ((const float4*)g)[t];
    float4 b4 = ((const float4*)be)[t];
    float o0 = (v[0] - mu) * rs * g4.x + b4.x;
    float o1 = (v[1] - mu) * rs * g4.y + b4.y;
    float o2 = (v[2] - mu) * rs * g4.z + b4.z;
    float o3 = (v[3] - mu) * rs * g4.w + b4.w;
    if (outf) {
        int orow = map_row(m, omb, obsd, oro);
        ((float4*)(outf + (size_t)orow * ldo))[t] = make_float4(o0, o1, o2, o3);
    }
    if (outb) {
        int brow = map_row(m, bmb, bbsd, bro);
        ((ushort4*)(outb + (size_t)brow * ldb))[t] =
            make_ushort4(f2b(o0), f2b(o1), f2b(o2), f2b(o3));
    }
}

static void run_scan(const unsigned short* dltb, const unsigned short* xcb, const float* bc,
                     const unsigned short* xzb, const float* A_log, const float* Dv,
                     float* part_h, float* part_s, unsigned short* out, int L, int NCr,
                     int c0, int lmin, hipStream_t stream)
{
    int blocks1 = BB * NCr * (DI / 256);
    int blocks2 = BB * (NCr - c0) * (DI / 256);
    if (L == SS) {
        scan_part1<8><<<blocks1, 256, 0, stream>>>(dltb, xcb, bc, A_log, part_h, part_s, L, NCr);
        scan_combine<<<BB * DI * DSN / 256, 256, 0, stream>>>(A_log, part_h, part_s, NCr, c0);
        scan_part2<8><<<blocks2, 256, 0, stream>>>(dltb, xcb, bc, xzb, A_log, Dv, part_h, out, L, NCr, c0, lmin);
    } else {
        scan_part1<24><<<blocks1, 256, 0, stream>>>(dltb, xcb, bc, A_log, part_h, part_s, L, NCr);
        scan_combine<<<BB * DI * DSN / 256, 256, 0, stream>>>(A_log, part_h, part_s, NCr, c0);
        scan_part2<24><<<blocks2, 256, 0, stream>>>(dltb, xcb, bc, xzb, A_log, Dv, part_h, out, L, NCr, c0, lmin);
    }
}

extern "C" void kernel_launch(void* const* d_in, const int* in_sizes, int n_in,
                              void* d_out, int out_size, void* d_ws, size_t ws_size,
                              hipStream_t stream)
{
    const float* tgt       = (const float*)d_in[0];
    const float* memory    = (const float*)d_in[1];
    const float* s_in_w    = (const float*)d_in[2];
    const float* s_conv_w  = (const float*)d_in[3];
    const float* s_conv_b  = (const float*)d_in[4];
    const float* s_xproj_w = (const float*)d_in[5];
    const float* s_dt_w    = (const float*)d_in[6];
    const float* s_dt_b    = (const float*)d_in[7];
    const float* s_A_log   = (const float*)d_in[8];
    const float* s_D_vec   = (const float*)d_in[9];
    const float* s_out_w   = (const float*)d_in[10];
    const float* c_in_w    = (const float*)d_in[11];
    const float* c_conv_w  = (const float*)d_in[12];
    const float* c_conv_b  = (const float*)d_in[13];
    const float* c_xproj_w = (const float*)d_in[14];
    const float* c_dt_w    = (const float*)d_in[15];
    const float* c_dt_b    = (const float*)d_in[16];
    const float* c_A_log   = (const float*)d_in[17];
    const float* c_D_vec   = (const float*)d_in[18];
    const float* c_out_w   = (const float*)d_in[19];
    const float* ln1_g     = (const float*)d_in[20];
    const float* ln1_b     = (const float*)d_in[21];
    const float* ln2_g     = (const float*)d_in[22];
    const float* ln2_b     = (const float*)d_in[23];
    const float* ln3_g     = (const float*)d_in[24];
    const float* ln3_b     = (const float*)d_in[25];
    const float* ffn_w1    = (const float*)d_in[26];
    const float* ffn_b1    = (const float*)d_in[27];
    const float* ffn_w2    = (const float*)d_in[28];
    const float* ffn_b2    = (const float*)d_in[29];
    float* outp = (float*)d_out;

    // ---- workspace layout ----
    float* ws     = (float*)d_ws;
    float* bc     = ws;                     // 393216  (12288 x 32: B|C)
    float* t1     = bc     + 393216;        // 2097152
    float* tbuf   = t1     + 2097152;       // 2097152
    float* part_h = tbuf   + 2097152;       // region 8388608 (B*64*DSN*DI, [b][c][s][d])
    float* proj   = part_h;                 // alias: 2097152 (dead during scans)
    float* pparts = part_h + 2097152;       // alias: 3 x 2097152 split-K partials
    float* pxd    = part_h;                 // alias: XDBL split-K partials (Z*M*64 <= 3.15M)
    float* part_s = part_h + 8388608;       // 524288  (B*64*DI)
    unsigned short* ub      = (unsigned short*)(part_s + 524288);
    unsigned short* dltb    = ub;                   // 12582912 (bf16 delta; ffnout aliases)
    unsigned short* catb    = dltb    + 12582912;   // 6291456 (dead after cross in-proj)
    unsigned short* tgtb    = catb    + 6291456;    // 2097152
    unsigned short* xzb     = tgtb    + 2097152;    // 25165824 (also fbuf alias)
    unsigned short* xcb     = xzb     + 25165824;   // 12582912
    unsigned short* ygb     = xcb     + 12582912;   // 12582912
    unsigned short* tbbf    = ygb     + 12582912;   // 2097152
    unsigned short* s_in_wb = tbbf    + 2097152;    // 1048576  (6-weight block, contiguous)
    unsigned short* c_in_wb = s_in_wb + 1048576;    // 1048576
    unsigned short* s_out_wb= c_in_wb + 1048576;    // 524288
    unsigned short* c_out_wb= s_out_wb+ 524288;     // 524288
    unsigned short* w1b     = c_out_wb+ 524288;     // 1048576
    unsigned short* w2b     = w1b     + 1048576;    // 1048576
    unsigned short* xprojb_s= w2b     + 1048576;    // 131072 (128 x 1024, padded)
    unsigned short* xprojb_c= xprojb_s+ 131072;     // 131072
    unsigned short* dtwb_s  = xprojb_c+ 131072;     // 65536  (1024 x 64, padded)
    unsigned short* dtwb_c  = dtwb_s  + 65536;      // 65536
    unsigned short* dtb     = dtwb_c  + 65536;      // 786432 (12288 x 64: dt | zeros)
    unsigned short* fbuf    = xzb;                  // FFN hidden alias
    float* ffnout  = (float*)dltb;                  // alias (dltb dead after cross scan)
    float* fparts  = ffnout + 2097152;              // 3 partials (extends into dead catb)

    // ---- fused prologue ----
    {
        PrepPtrs pp;
        pp.tgt = tgt; pp.mem = memory;
        pp.w[0]=s_in_w; pp.w[1]=c_in_w; pp.w[2]=s_out_w; pp.w[3]=c_out_w; pp.w[4]=ffn_w1; pp.w[5]=ffn_w2;
        pp.xpj_s = s_xproj_w; pp.xpj_c = c_xproj_w;
        pp.dtw_s = s_dt_w;    pp.dtw_c = c_dt_w;
        pp.tgtb = tgtb; pp.catb = catb; pp.wb = s_in_wb;
        pp.xprojb_s = xprojb_s; pp.xprojb_c = xprojb_c;
        pp.dtwb_s = dtwb_s; pp.dtwb_c = dtwb_c;
        prep_kernel<<<11648, 256, 0, stream>>>(pp);
    }

    // ---- self mamba (L=512, M=4096) ----
    mgemm_kernel<<<dim3(2048/128, 4096/128), 256, 0, stream>>>(
        tgtb, 4096, 0, 0, s_in_wb, nullptr, nullptr, xzb, nullptr, nullptr, 2048, 512, ACT_NONE,
        4096, 0, 0, 2048, 0, 0,  0, 0,0,0, 0, 0,0,0, 0);
    conv_silu_kernel<<<(BB*(SS/CONV_R)*128 + 255)/256, 256, 0, stream>>>(
        xzb, s_conv_w, s_conv_b, xcb, SS, BB*(SS/CONV_R)*128);
    // delta path stage 1 (split-K x4): x_dbl partials -> pxd; combine -> dt bf16 + bc fp32
    mgemm_kernel<<<dim3(1, 4096/128, 4), 256, 0, stream>>>(
        xcb, 4096, 0, 0, xprojb_s, nullptr, nullptr, nullptr, pxd, nullptr, 128, 1024, ACT_XDBL,
        4096, 0, 0, 0, 0, 0,  0, 0,0,0, 0, 0,0,0, 0);
    xdbl_combine<<<4096*16/256, 256, 0, stream>>>(pxd, dtb, bc, 4096, 4);
    // delta path stage 2: delta = softplus(dt @ dt_w^T + dt_b), K=64 (one k-iter)
    mgemm_kernel<<<dim3(1024/128, 4096/128), 256, 0, stream>>>(
        dtb, 4096, 0, 0, dtwb_s, s_dt_b, nullptr, dltb, nullptr, nullptr, 1024, 64, ACT_DELTA,
        4096, 0, 0, 1024, 0, 0,  0, 0,0,0, 0, 0,0,0, 0);
    run_scan(dltb, xcb, bc, xzb, s_A_log, s_D_vec, part_h, part_s, ygb, SS, 64, 0, 0, stream);
    mgemm_kernel<<<dim3(512/128, 4096/128, 4), 256, 0, stream>>>(
        ygb, 4096, 0, 0, s_out_wb, nullptr, proj, nullptr, nullptr, pparts, 512, 1024, ACT_NONE,
        4096, 0, 0, 512, 0, 2097152,  0, 0,0,0, 0, 0,0,0, 0);
    addln_kernel<<<4096, 128, 0, stream>>>(
        tgt, 4096, 0, 0, DM, proj, pparts, 3, 2097152, ln1_g, ln1_b,
        t1, 4096, 0, 0, DM, catb, 512, 1536, 1024, DM);

    // ---- cross mamba (L=1536, M=12288) ----
    // merged x-half (by<96: all 12288 rows, W rows 0..1023 -> cols 0..1023) and
    // z-half (by>=96: tgt rows only, W rows 1024..2047 -> cols 1024..2047).
    // 1024-block grid -> pipe wins here (A/B vs mgemm_kernel: 48.5 -> <=41 us).
    mgemm_pipe<<<dim3(1024/128, 96 + 32), 512, 0, stream>>>(
        catb, 12288, 0, 0, c_in_wb, nullptr, xzb, 512, ACT_NONE,
        12288, 0, 0, 2048, 0,
        96, 512, 1536, 1024, 1024 * 512, 512, 1536, 1024, 1024);
    conv_silu_kernel<<<(BB*(LCAT/CONV_R)*128 + 255)/256, 256, 0, stream>>>(
        xzb, c_conv_w, c_conv_b, xcb, LCAT, BB*(LCAT/CONV_R)*128);
    mgemm_kernel<<<dim3(1, 12288/128, 4), 256, 0, stream>>>(
        xcb, 12288, 0, 0, xprojb_c, nullptr, nullptr, nullptr, pxd, nullptr, 128, 1024, ACT_XDBL,
        12288, 0, 0, 0, 0, 0,  0, 0,0,0, 0, 0,0,0, 0);
    xdbl_combine<<<12288*16/256, 256, 0, stream>>>(pxd, dtb, bc, 12288, 4);
    mgemm_kernel<<<dim3(1024/128, 12288/128), 256, 0, stream>>>(
        dtb, 12288, 0, 0, dtwb_c, c_dt_b, nullptr, dltb, nullptr, nullptr, 1024, 64, ACT_DELTA,
        12288, 0, 0, 1024, 0, 0,  0, 0,0,0, 0, 0,0,0, 0);
    // part2 restricted: CH=24, chunk 42 starts at row 1008 (<1024); lmin guards 1008..1023
    run_scan(dltb, xcb, bc, xzb, c_A_log, c_D_vec, part_h, part_s, ygb, LCAT, 64, 42, 1024, stream);
    mgemm_kernel<<<dim3(512/128, 4096/128, 4), 256, 0, stream>>>(
        ygb, 512, 1536, 1024, c_out_wb, nullptr, proj, nullptr, nullptr, pparts, 512, 1024, ACT_NONE,
        4096, 0, 0, 512, 0, 2097152,  0, 0,0,0, 0, 0,0,0, 0);
    addln_kernel<<<4096, 128, 0, stream>>>(
        t1, 4096, 0, 0, DM, proj, pparts, 3, 2097152, ln2_g, ln2_b,
        tbuf, 4096, 0, 0, DM, tbbf, 4096, 0, 0, DM);

    // ---- FFN ----
    mgemm_kernel<<<dim3(2048/128, 4096/128), 256, 0, stream>>>(
        tbbf, 4096, 0, 0, w1b, ffn_b1, nullptr, fbuf, nullptr, nullptr, 2048, 512, ACT_RELU,
        4096, 0, 0, 2048, 0, 0,  0, 0,0,0, 0, 0,0,0, 0);
    mgemm_kernel<<<dim3(512/128, 4096/128, 4), 256, 0, stream>>>(
        fbuf, 4096, 0, 0, w2b, ffn_b2, ffnout, nullptr, nullptr, fparts, 512, 2048, ACT_NONE,
        4096, 0, 0, 512, 0, 2097152,  0, 0,0,0, 0, 0,0,0, 0);
    addln_kernel<<<4096, 128, 0, stream>>>(
        tbuf, 4096, 0, 0, DM, ffnout, fparts, 3, 2097152, ln3_g, ln3_b,
        outp, 4096, 0, 0, DM, nullptr, 0, 0, 0, 0);
}